// Round 5
// baseline (332.648 us; speedup 1.0000x reference)
//
#include <hip/hip_runtime.h>
#include <stdint.h>

// Problem constants (fixed by reference)
#define BB    16
#define NN    1000
#define DD    2048
#define KK    256
#define SIG   0.05f
#define INVN  (1.0f / 1000.0f)

#define T1    256
#define NBUCK 4096   // 12-bit high-bits histogram

// ---------------- Kernel 1: per-row exact top-K ranks -> transposed uint16 --
// One block = one (b,n) row, 256 threads x 8 elements, ~16.5 KB LDS ->
// 8 blocks/CU (32 waves = occupancy cap; R2->R3 showed blocks/CU is the lever).
// Packed uint16 histogram (counts <= 2048, carry-safe half-word LDS atomics) ->
// suffix counts F(b) -> crossing bucket b* -> compaction into sF cursors with
// 32-bit truncated keys (within-bucket compares only need low-20 value bits +
// 11-bit reversed index) -> self-rank (compacting thread knows its bucket) ->
// direct scatter idxT[b][rank][n] = d.
__global__ __launch_bounds__(T1, 8) void ptopk_rank(
    const float* __restrict__ x,
    const float* __restrict__ noise,
    uint16_t* __restrict__ idxT)
{
    __shared__ __align__(16) uint16_t sF[NBUCK + 16];  // hist -> F(b); pad zeroed:
                                                       // cursor for bucket 4095 lives at [4096]
    __shared__ __align__(16) uint32_t sCand[DD];       // truncated keys, bucket-grouped
    __shared__ uint32_t sWS[4];                        // per-wave scan totals
    __shared__ uint32_t sBstar;                        // crossing bucket

    const int t    = threadIdx.x;
    const int lane = t & 63;
    const int w    = t >> 6;
    const int row  = blockIdx.x;
    const int b    = row / NN;
    const int n    = row - b * NN;

    uint32_t* sFw = (uint32_t*)sF;

    // ---- init sF: 8224 B = 514 uint4 ----
    uint4 z; z.x = z.y = z.z = z.w = 0u;
    uint4* sF4 = (uint4*)sF;
    sF4[t]        = z;
    sF4[t + T1]   = z;
    if (t < 2) sF4[2 * T1 + t] = z;
    __syncthreads();

    // ---- load 8 elements (two coalesced float4 per array), keys, histogram --
    const float4* nrow = (const float4*)(noise + (size_t)row * DD);
    const float4* xrow = (const float4*)(x + (size_t)b * DD);
    float4 na = nrow[t], nb = nrow[t + T1];
    float4 xa = xrow[t], xb = xrow[t + T1];

    float v[8];
    // match numpy: separate rounded mul and add (no FMA contraction)
    v[0] = __fadd_rn(xa.x, __fmul_rn(na.x, SIG));
    v[1] = __fadd_rn(xa.y, __fmul_rn(na.y, SIG));
    v[2] = __fadd_rn(xa.z, __fmul_rn(na.z, SIG));
    v[3] = __fadd_rn(xa.w, __fmul_rn(na.w, SIG));
    v[4] = __fadd_rn(xb.x, __fmul_rn(nb.x, SIG));
    v[5] = __fadd_rn(xb.y, __fmul_rn(nb.y, SIG));
    v[6] = __fadd_rn(xb.z, __fmul_rn(nb.z, SIG));
    v[7] = __fadd_rn(xb.w, __fmul_rn(nb.w, SIG));

    uint32_t u[8];
    #pragma unroll
    for (int i = 0; i < 8; ++i) {
        uint32_t ub = __float_as_uint(v[i]);
        // order-preserving map: u = ub ^ (asr31(ub) | 0x80000000)
        u[i] = ub ^ (uint32_t)(((int32_t)ub >> 31) | (int32_t)0x80000000);
        uint32_t bk = u[i] >> 20;
        atomicAdd(&sFw[bk >> 1], 1u << ((bk & 1) << 4));   // packed uint16 count
    }
    __syncthreads();

    // ---- suffix counts F(b): thread owns buckets [16t, 16t+16) ----
    uint4 ca = ((const uint4*)sF)[2 * t];
    uint4 cb = ((const uint4*)sF)[2 * t + 1];
    uint32_t h[16];
    h[0]  = ca.x & 0xFFFFu;  h[1]  = ca.x >> 16;
    h[2]  = ca.y & 0xFFFFu;  h[3]  = ca.y >> 16;
    h[4]  = ca.z & 0xFFFFu;  h[5]  = ca.z >> 16;
    h[6]  = ca.w & 0xFFFFu;  h[7]  = ca.w >> 16;
    h[8]  = cb.x & 0xFFFFu;  h[9]  = cb.x >> 16;
    h[10] = cb.y & 0xFFFFu;  h[11] = cb.y >> 16;
    h[12] = cb.z & 0xFFFFu;  h[13] = cb.z >> 16;
    h[14] = cb.w & 0xFFFFu;  h[15] = cb.w >> 16;
    uint32_t csum = 0;
    #pragma unroll
    for (int i = 0; i < 16; ++i) csum += h[i];

    // wave-level inclusive suffix scan (higher lane = higher buckets)
    uint32_t s = csum;
    #pragma unroll
    for (int ofs = 1; ofs < 64; ofs <<= 1) {
        uint32_t o = __shfl_down(s, ofs, 64);
        s += (lane + ofs < 64) ? o : 0u;
    }
    if (lane == 0) sWS[w] = s;
    __syncthreads();
    if (t == 0) {                 // exclusive suffix over 4 wave totals
        uint32_t run = 0;
        #pragma unroll
        for (int i = 3; i >= 0; --i) { uint32_t tmp = sWS[i]; sWS[i] = run; run += tmp; }
    }
    __syncthreads();

    uint32_t F[17];
    F[16] = sWS[w] + (s - csum);              // F(16t+16)
    #pragma unroll
    for (int i = 15; i >= 0; --i) F[i] = F[i + 1] + h[i];

    // crossing bucket b*: F(b*) >= K > F(b*+1); exactly one thread finds it
    #pragma unroll
    for (int i = 0; i < 16; ++i)
        if (F[i] >= KK && F[i + 1] < KK) sBstar = (uint32_t)(16 * t + i);

    // pack F back (uint16) and publish
    uint4 fa, fb;
    fa.x = F[0]  | (F[1]  << 16);  fa.y = F[2]  | (F[3]  << 16);
    fa.z = F[4]  | (F[5]  << 16);  fa.w = F[6]  | (F[7]  << 16);
    fb.x = F[8]  | (F[9]  << 16);  fb.y = F[10] | (F[11] << 16);
    fb.z = F[12] | (F[13] << 16);  fb.w = F[14] | (F[15] << 16);
    ((uint4*)sF)[2 * t]     = fa;
    ((uint4*)sF)[2 * t + 1] = fb;
    __syncthreads();

    // ---- compact candidates (bucket >= b*) ----
    // cursor for bucket bk is sF[bk+1]; after compaction sF[bk+1] == F(bk).
    // 32-bit key: low20(u) << 11 | (2047-d)  (ties rank lower d first; top-12
    // bits equal within a bucket so truncation preserves within-bucket order)
    const uint32_t bstar = sBstar;
    #pragma unroll
    for (int i = 0; i < 8; ++i) {
        uint32_t bk = u[i] >> 20;
        if (bk >= bstar) {
            uint32_t ci  = bk + 1;
            uint32_t sh  = (ci & 1) << 4;
            uint32_t old = atomicAdd(&sFw[ci >> 1], 1u << sh);
            uint32_t pos = (old >> sh) & 0xFFFFu;
            int d = (i < 4) ? (4 * t + i) : (1024 + 4 * t + (i - 4));
            sCand[pos] = ((u[i] & 0xFFFFFu) << 11) | (uint32_t)(DD - 1 - d);
        }
    }
    __syncthreads();

    // ---- self-rank: each thread ranks the candidates it compacted ----
    // post-compaction: sF[bk+1] = F(bk) (hi), sF[bk+2] = F(bk+1) (lo)
    #pragma unroll
    for (int i = 0; i < 8; ++i) {
        uint32_t bk = u[i] >> 20;
        if (bk >= bstar) {
            int d = (i < 4) ? (4 * t + i) : (1024 + 4 * t + (i - 4));
            uint32_t key = ((u[i] & 0xFFFFFu) << 11) | (uint32_t)(DD - 1 - d);
            uint32_t hi = sF[bk + 1];
            uint32_t lo = sF[bk + 2];
            uint32_t rank = lo;
            for (uint32_t j = lo; j < hi; ++j)
                rank += (sCand[j] > key) ? 1u : 0u;
            if (rank < KK)
                idxT[((size_t)(b * KK + (int)rank)) * NN + n] = (uint16_t)d;
        }
    }
}

// ---------------- Kernel 2: accumulate indicators, dense write, no atomics --
// One block = one (b,k) pair: 4096 blocks x 128 threads, 4 KB LDS histogram.
// Reads its 1000 indices as 125 contiguous uint4 (L2-resident), run-length
// aggregates before LDS atomics (rank-k index is stable across n), writes
// out[b][k][:] dense.
#define T2 128
__global__ __launch_bounds__(T2, 8) void ptopk_accum(
    const uint16_t* __restrict__ idxT,
    float* __restrict__ out)
{
    __shared__ __align__(16) uint32_t hist[DD / 2];   // 1024 words = 4 KB

    const int t   = threadIdx.x;
    const int bkx = blockIdx.x;          // = b*KK + k

    uint4 z; z.x = z.y = z.z = z.w = 0u;
    ((uint4*)hist)[t]       = z;
    ((uint4*)hist)[t + T2]  = z;
    __syncthreads();

    // 1000 uint16 = 125 uint4 per (b,k) row, contiguous
    if (t < 125) {
        uint4 v = ((const uint4*)(idxT + (size_t)bkx * NN))[t];
        uint16_t d[8];
        d[0] = (uint16_t)(v.x & 0xFFFFu); d[1] = (uint16_t)(v.x >> 16);
        d[2] = (uint16_t)(v.y & 0xFFFFu); d[3] = (uint16_t)(v.y >> 16);
        d[4] = (uint16_t)(v.z & 0xFFFFu); d[5] = (uint16_t)(v.z >> 16);
        d[6] = (uint16_t)(v.w & 0xFFFFu); d[7] = (uint16_t)(v.w >> 16);
        // run-length aggregate consecutive equal indices -> one atomic per run
        uint16_t cur = d[0];
        uint32_t run = 1;
        #pragma unroll
        for (int i = 1; i < 8; ++i) {
            if (d[i] == cur) { run++; }
            else {
                atomicAdd(&hist[cur >> 1], run << ((cur & 1) << 4));
                cur = d[i]; run = 1;
            }
        }
        atomicAdd(&hist[cur >> 1], run << ((cur & 1) << 4));
    }
    __syncthreads();

    // dense coalesced write: 2048 floats; each thread 2 uint4 -> 4 float4
    float4* out4 = (float4*)(out + (size_t)bkx * DD);
    #pragma unroll
    for (int i = 0; i < 2; ++i) {
        int j = i * T2 + t;
        uint4 wv = ((const uint4*)hist)[j];
        float4 f0, f1;
        f0.x = (float)(wv.x & 0xFFFFu) * INVN;  f0.y = (float)(wv.x >> 16) * INVN;
        f0.z = (float)(wv.y & 0xFFFFu) * INVN;  f0.w = (float)(wv.y >> 16) * INVN;
        f1.x = (float)(wv.z & 0xFFFFu) * INVN;  f1.y = (float)(wv.z >> 16) * INVN;
        f1.z = (float)(wv.w & 0xFFFFu) * INVN;  f1.w = (float)(wv.w >> 16) * INVN;
        out4[2 * j]     = f0;
        out4[2 * j + 1] = f1;
    }
}

extern "C" void kernel_launch(void* const* d_in, const int* in_sizes, int n_in,
                              void* d_out, int out_size, void* d_ws, size_t ws_size,
                              hipStream_t stream) {
    const float* x     = (const float*)d_in[0];
    const float* noise = (const float*)d_in[1];
    float* out         = (float*)d_out;
    uint16_t* idxT     = (uint16_t*)d_ws;    // BB*KK*NN*2 = 8.2 MB, transposed

    hipLaunchKernelGGL(ptopk_rank,
                       dim3(BB * NN), dim3(T1), 0, stream,
                       x, noise, idxT);
    hipLaunchKernelGGL(ptopk_accum,
                       dim3(BB * KK), dim3(T2), 0, stream,
                       idxT, out);
}

// Round 6
// 235.966 us; speedup vs baseline: 1.4097x; 1.4097x over previous
//
#include <hip/hip_runtime.h>
#include <stdint.h>

// Problem constants (fixed by reference)
#define BB    16
#define NN    1000
#define DD    2048
#define KK    256
#define SIG   0.05f
#define INVN  (1.0f / 1000.0f)

#define T1    256
#define NBUCK 4096   // 12-bit high-bits histogram

// ---------------- Kernel 1: per-row exact top-K ranks -> transposed uint16 --
// One block = one (b,n) row, 256 threads x 8 elements, ~21 KB LDS ->
// 7 blocks/CU (28 waves). Packed uint16 histogram (counts <= 2048, carry-safe
// half-word LDS atomics) -> suffix counts F(b) -> crossing bucket b* ->
// compaction into sF cursors with 32-bit truncated keys + uint16 bucket aux
// -> DISTRIBUTED rank loop (bucket-grouped candidates => balanced wave64
// work; R5's self-rank diverged 4-8x) -> scatter idxT[b][rank][n] = d.
__global__ __launch_bounds__(T1, 8) void ptopk_rank(
    const float* __restrict__ x,
    const float* __restrict__ noise,
    uint16_t* __restrict__ idxT)
{
    __shared__ __align__(16) uint16_t sF[NBUCK + 16];  // hist -> F(b); pad zeroed
    __shared__ __align__(16) uint32_t sCand[DD];       // truncated keys, bucket-grouped
    __shared__ __align__(16) uint16_t sCandBk[DD];     // bucket id per candidate slot
    __shared__ uint16_t sIdx[KK];                      // rank -> d
    __shared__ uint32_t sWS[4];                        // per-wave scan totals
    __shared__ uint32_t sBstar;                        // crossing bucket
    __shared__ uint32_t sC;                            // candidate count

    const int t    = threadIdx.x;
    const int lane = t & 63;
    const int w    = t >> 6;
    const int row  = blockIdx.x;
    const int b    = row / NN;
    const int n    = row - b * NN;

    uint32_t* sFw = (uint32_t*)sF;

    // ---- init sF: 8224 B = 514 uint4 (covers pad through sF[4111]) ----
    uint4 z; z.x = z.y = z.z = z.w = 0u;
    uint4* sF4 = (uint4*)sF;
    sF4[t]        = z;
    sF4[t + T1]   = z;
    if (t < 2) sF4[2 * T1 + t] = z;
    __syncthreads();

    // ---- load 8 elements (two coalesced float4 per array), keys, histogram --
    const float4* nrow = (const float4*)(noise + (size_t)row * DD);
    const float4* xrow = (const float4*)(x + (size_t)b * DD);
    float4 na = nrow[t], nb = nrow[t + T1];
    float4 xa = xrow[t], xb = xrow[t + T1];

    float v[8];
    // match numpy: separate rounded mul and add (no FMA contraction)
    v[0] = __fadd_rn(xa.x, __fmul_rn(na.x, SIG));
    v[1] = __fadd_rn(xa.y, __fmul_rn(na.y, SIG));
    v[2] = __fadd_rn(xa.z, __fmul_rn(na.z, SIG));
    v[3] = __fadd_rn(xa.w, __fmul_rn(na.w, SIG));
    v[4] = __fadd_rn(xb.x, __fmul_rn(nb.x, SIG));
    v[5] = __fadd_rn(xb.y, __fmul_rn(nb.y, SIG));
    v[6] = __fadd_rn(xb.z, __fmul_rn(nb.z, SIG));
    v[7] = __fadd_rn(xb.w, __fmul_rn(nb.w, SIG));

    uint32_t u[8];
    #pragma unroll
    for (int i = 0; i < 8; ++i) {
        uint32_t ub = __float_as_uint(v[i]);
        // order-preserving map: u = ub ^ (asr31(ub) | 0x80000000)
        u[i] = ub ^ (uint32_t)(((int32_t)ub >> 31) | (int32_t)0x80000000);
        uint32_t bk = u[i] >> 20;
        atomicAdd(&sFw[bk >> 1], 1u << ((bk & 1) << 4));   // packed uint16 count
    }
    __syncthreads();

    // ---- suffix counts F(b): thread owns buckets [16t, 16t+16) ----
    uint4 ca = ((const uint4*)sF)[2 * t];
    uint4 cb = ((const uint4*)sF)[2 * t + 1];
    uint32_t h[16];
    h[0]  = ca.x & 0xFFFFu;  h[1]  = ca.x >> 16;
    h[2]  = ca.y & 0xFFFFu;  h[3]  = ca.y >> 16;
    h[4]  = ca.z & 0xFFFFu;  h[5]  = ca.z >> 16;
    h[6]  = ca.w & 0xFFFFu;  h[7]  = ca.w >> 16;
    h[8]  = cb.x & 0xFFFFu;  h[9]  = cb.x >> 16;
    h[10] = cb.y & 0xFFFFu;  h[11] = cb.y >> 16;
    h[12] = cb.z & 0xFFFFu;  h[13] = cb.z >> 16;
    h[14] = cb.w & 0xFFFFu;  h[15] = cb.w >> 16;
    uint32_t csum = 0;
    #pragma unroll
    for (int i = 0; i < 16; ++i) csum += h[i];

    // wave-level inclusive suffix scan (higher lane = higher buckets)
    uint32_t s = csum;
    #pragma unroll
    for (int ofs = 1; ofs < 64; ofs <<= 1) {
        uint32_t o = __shfl_down(s, ofs, 64);
        s += (lane + ofs < 64) ? o : 0u;
    }
    if (lane == 0) sWS[w] = s;
    __syncthreads();
    if (t == 0) {                 // exclusive suffix over 4 wave totals
        uint32_t run = 0;
        #pragma unroll
        for (int i = 3; i >= 0; --i) { uint32_t tmp = sWS[i]; sWS[i] = run; run += tmp; }
    }
    __syncthreads();

    uint32_t F[17];
    F[16] = sWS[w] + (s - csum);              // F(16t+16)
    #pragma unroll
    for (int i = 15; i >= 0; --i) F[i] = F[i + 1] + h[i];

    // crossing bucket b*: F(b*) >= K > F(b*+1); exactly one thread finds it
    #pragma unroll
    for (int i = 0; i < 16; ++i)
        if (F[i] >= KK && F[i + 1] < KK) { sBstar = (uint32_t)(16 * t + i); sC = F[i]; }

    // pack F back (uint16) and publish
    uint4 fa, fb;
    fa.x = F[0]  | (F[1]  << 16);  fa.y = F[2]  | (F[3]  << 16);
    fa.z = F[4]  | (F[5]  << 16);  fa.w = F[6]  | (F[7]  << 16);
    fb.x = F[8]  | (F[9]  << 16);  fb.y = F[10] | (F[11] << 16);
    fb.z = F[12] | (F[13] << 16);  fb.w = F[14] | (F[15] << 16);
    ((uint4*)sF)[2 * t]     = fa;
    ((uint4*)sF)[2 * t + 1] = fb;
    __syncthreads();

    // ---- compact candidates (bucket >= b*) ----
    // cursor for bucket bk is sF[bk+1] (starts at F(bk+1), ends at F(bk)).
    // 32-bit key: low20(u) << 11 | (2047-d); top-12 bits equal within a
    // bucket, so truncation preserves within-bucket order; reversed index
    // makes ties rank lower d first.
    const uint32_t bstar = sBstar;
    #pragma unroll
    for (int i = 0; i < 8; ++i) {
        uint32_t bk = u[i] >> 20;
        if (bk >= bstar) {
            uint32_t ci  = bk + 1;
            uint32_t sh  = (ci & 1) << 4;
            uint32_t old = atomicAdd(&sFw[ci >> 1], 1u << sh);
            uint32_t pos = (old >> sh) & 0xFFFFu;
            int d = (i < 4) ? (4 * t + i) : (1024 + 4 * t + (i - 4));
            sCand[pos]   = ((u[i] & 0xFFFFFu) << 11) | (uint32_t)(DD - 1 - d);
            sCandBk[pos] = (uint16_t)bk;
        }
    }
    __syncthreads();

    // ---- distributed rank loop: bucket-grouped => balanced wave work ----
    // post-compaction: sF[bk+1] = F(bk) (hi), sF[bk+2] = F(bk+1) (lo)
    const int C = (int)sC;
    for (int p = t; p < C; p += T1) {
        uint32_t key = sCand[p];
        int bk = (int)sCandBk[p];
        uint32_t hi = sF[bk + 1];
        uint32_t lo = sF[bk + 2];
        uint32_t rank = lo;
        for (uint32_t j = lo; j < hi; ++j)
            rank += (sCand[j] > key) ? 1u : 0u;
        if (rank < KK)
            sIdx[rank] = (uint16_t)(DD - 1 - (int)(key & 0x7FFu));
    }
    __syncthreads();

    // ---- scattered transposed store: idxT[(b*K + rank)*N + n] = d ----
    // (2B stores; costs ~6 us of write amplification in K1 but makes K2's
    //  reads fully coalesced — measured net win in R4)
    if (t < KK)
        idxT[((size_t)(b * KK + t)) * NN + n] = sIdx[t];
}

// ---------------- Kernel 2: accumulate indicators, dense write, no atomics --
// One block = one (b,k) pair: 4096 blocks x 128 threads, 4 KB LDS histogram.
// Reads its 1000 indices as 125 contiguous uint4 (L2-resident), run-length
// aggregates before LDS atomics (rank-k index is stable across n), writes
// out[b][k][:] dense.
#define T2 128
__global__ __launch_bounds__(T2, 8) void ptopk_accum(
    const uint16_t* __restrict__ idxT,
    float* __restrict__ out)
{
    __shared__ __align__(16) uint32_t hist[DD / 2];   // 1024 words = 4 KB

    const int t   = threadIdx.x;
    const int bkx = blockIdx.x;          // = b*KK + k

    uint4 z; z.x = z.y = z.z = z.w = 0u;
    ((uint4*)hist)[t]       = z;
    ((uint4*)hist)[t + T2]  = z;
    __syncthreads();

    // 1000 uint16 = 125 uint4 per (b,k) row, contiguous
    if (t < 125) {
        uint4 v = ((const uint4*)(idxT + (size_t)bkx * NN))[t];
        uint16_t d[8];
        d[0] = (uint16_t)(v.x & 0xFFFFu); d[1] = (uint16_t)(v.x >> 16);
        d[2] = (uint16_t)(v.y & 0xFFFFu); d[3] = (uint16_t)(v.y >> 16);
        d[4] = (uint16_t)(v.z & 0xFFFFu); d[5] = (uint16_t)(v.z >> 16);
        d[6] = (uint16_t)(v.w & 0xFFFFu); d[7] = (uint16_t)(v.w >> 16);
        // run-length aggregate consecutive equal indices -> one atomic per run
        uint16_t cur = d[0];
        uint32_t run = 1;
        #pragma unroll
        for (int i = 1; i < 8; ++i) {
            if (d[i] == cur) { run++; }
            else {
                atomicAdd(&hist[cur >> 1], run << ((cur & 1) << 4));
                cur = d[i]; run = 1;
            }
        }
        atomicAdd(&hist[cur >> 1], run << ((cur & 1) << 4));
    }
    __syncthreads();

    // dense coalesced write: 2048 floats; each thread 2 uint4 -> 4 float4
    float4* out4 = (float4*)(out + (size_t)bkx * DD);
    #pragma unroll
    for (int i = 0; i < 2; ++i) {
        int j = i * T2 + t;
        uint4 wv = ((const uint4*)hist)[j];
        float4 f0, f1;
        f0.x = (float)(wv.x & 0xFFFFu) * INVN;  f0.y = (float)(wv.x >> 16) * INVN;
        f0.z = (float)(wv.y & 0xFFFFu) * INVN;  f0.w = (float)(wv.y >> 16) * INVN;
        f1.x = (float)(wv.z & 0xFFFFu) * INVN;  f1.y = (float)(wv.z >> 16) * INVN;
        f1.z = (float)(wv.w & 0xFFFFu) * INVN;  f1.w = (float)(wv.w >> 16) * INVN;
        out4[2 * j]     = f0;
        out4[2 * j + 1] = f1;
    }
}

extern "C" void kernel_launch(void* const* d_in, const int* in_sizes, int n_in,
                              void* d_out, int out_size, void* d_ws, size_t ws_size,
                              hipStream_t stream) {
    const float* x     = (const float*)d_in[0];
    const float* noise = (const float*)d_in[1];
    float* out         = (float*)d_out;
    uint16_t* idxT     = (uint16_t*)d_ws;    // BB*KK*NN*2 = 8.2 MB, transposed

    hipLaunchKernelGGL(ptopk_rank,
                       dim3(BB * NN), dim3(T1), 0, stream,
                       x, noise, idxT);
    hipLaunchKernelGGL(ptopk_accum,
                       dim3(BB * KK), dim3(T2), 0, stream,
                       idxT, out);
}

// Round 7
// 228.624 us; speedup vs baseline: 1.4550x; 1.0321x over previous
//
#include <hip/hip_runtime.h>
#include <stdint.h>

// Problem constants (fixed by reference)
#define BB    16
#define NN    1000
#define DD    2048
#define KK    256
#define SIG   0.05f
#define INVN  (1.0f / 1000.0f)

#define T1    256
#define NBUCK 4096   // 12-bit high-bits histogram

// ---------------- Kernel 1: per-row exact top-K ranks -> transposed uint16 --
// One block = one (b,n) row, 256 threads x 8 elements, ~21 KB LDS ->
// 7 blocks/CU (28 waves).
// XCD-swizzled row mapping: consecutive n on the same XCD so the 2B scatter
// stores to idxT accumulate full cachelines in ONE XCD's L2 (R6 showed 8x
// write amplification from round-robin XCD dispatch).
// Packed uint16 histogram -> packed pair-sum suffix scan (no unpack) ->
// crossing thread finds b* -> ONLY threads covering buckets >= b* unpack and
// publish F (wave-uniform, ~25% of threads) -> compaction into sF cursors ->
// distributed bucket-grouped rank loop -> direct global scatter of ranks.
__global__ __launch_bounds__(T1, 8) void ptopk_rank(
    const float* __restrict__ x,
    const float* __restrict__ noise,
    uint16_t* __restrict__ idxT)
{
    __shared__ __align__(16) uint16_t sF[NBUCK + 16];  // hist -> F(b); pad zeroed
    __shared__ __align__(16) uint32_t sCand[DD];       // truncated keys, bucket-grouped
    __shared__ __align__(16) uint16_t sCandBk[DD];     // bucket id per candidate slot
    __shared__ uint32_t sWS[4];                        // per-wave scan totals
    __shared__ uint32_t sBstar;                        // crossing bucket
    __shared__ uint32_t sC;                            // candidate count

    const int t    = threadIdx.x;
    const int lane = t & 63;
    const int w    = t >> 6;
    // XCD swizzle: block i runs on XCD (i&7); give it row so that rows are
    // consecutive within an XCD -> idxT lines written by a single L2.
    const int row  = (blockIdx.x & 7) * (BB * NN / 8) + (blockIdx.x >> 3);
    const int b    = row / NN;
    const int n    = row - b * NN;

    uint32_t* sFw = (uint32_t*)sF;

    // ---- init sF: 8224 B = 514 uint4 (covers pad through sF[4111]) ----
    uint4 z; z.x = z.y = z.z = z.w = 0u;
    uint4* sF4 = (uint4*)sF;
    sF4[t]        = z;
    sF4[t + T1]   = z;
    if (t < 2) sF4[2 * T1 + t] = z;
    __syncthreads();

    // ---- load 8 elements (two coalesced float4 per array), keys, histogram --
    const float4* nrow = (const float4*)(noise + (size_t)row * DD);
    const float4* xrow = (const float4*)(x + (size_t)b * DD);
    float4 na = nrow[t], nb = nrow[t + T1];
    float4 xa = xrow[t], xb = xrow[t + T1];

    float v[8];
    // match numpy: separate rounded mul and add (no FMA contraction)
    v[0] = __fadd_rn(xa.x, __fmul_rn(na.x, SIG));
    v[1] = __fadd_rn(xa.y, __fmul_rn(na.y, SIG));
    v[2] = __fadd_rn(xa.z, __fmul_rn(na.z, SIG));
    v[3] = __fadd_rn(xa.w, __fmul_rn(na.w, SIG));
    v[4] = __fadd_rn(xb.x, __fmul_rn(nb.x, SIG));
    v[5] = __fadd_rn(xb.y, __fmul_rn(nb.y, SIG));
    v[6] = __fadd_rn(xb.z, __fmul_rn(nb.z, SIG));
    v[7] = __fadd_rn(xb.w, __fmul_rn(nb.w, SIG));

    uint32_t u[8];
    #pragma unroll
    for (int i = 0; i < 8; ++i) {
        uint32_t ub = __float_as_uint(v[i]);
        // order-preserving map: u = ub ^ (asr31(ub) | 0x80000000)
        u[i] = ub ^ (uint32_t)(((int32_t)ub >> 31) | (int32_t)0x80000000);
        uint32_t bk = u[i] >> 20;
        atomicAdd(&sFw[bk >> 1], 1u << ((bk & 1) << 4));   // packed uint16 count
    }
    __syncthreads();

    // ---- chunk sum via packed pair-adds (counts <= 2048 so pair-sums
    //      <= 16384: no carry between halves; NO unpack needed) ----
    uint4 ca = ((const uint4*)sF)[2 * t];
    uint4 cb = ((const uint4*)sF)[2 * t + 1];
    uint32_t S = ca.x + ca.y + ca.z + ca.w + cb.x + cb.y + cb.z + cb.w;
    uint32_t csum = (S & 0xFFFFu) + (S >> 16);

    // wave-level inclusive suffix scan (higher lane = higher buckets)
    uint32_t s = csum;
    #pragma unroll
    for (int ofs = 1; ofs < 64; ofs <<= 1) {
        uint32_t o = __shfl_down(s, ofs, 64);
        s += (lane + ofs < 64) ? o : 0u;
    }
    if (lane == 0) sWS[w] = s;
    __syncthreads();
    if (t == 0) {                 // exclusive suffix over 4 wave totals
        uint32_t run = 0;
        #pragma unroll
        for (int i = 3; i >= 0; --i) { uint32_t tmp = sWS[i]; sWS[i] = run; run += tmp; }
    }
    __syncthreads();

    const uint32_t above = sWS[w] + (s - csum);        // F(16t+16)

    // ---- exactly one thread's chunk contains the crossing; it unpacks ----
    if (above < KK && above + csum >= KK) {
        uint32_t h[16];
        h[0]  = ca.x & 0xFFFFu;  h[1]  = ca.x >> 16;
        h[2]  = ca.y & 0xFFFFu;  h[3]  = ca.y >> 16;
        h[4]  = ca.z & 0xFFFFu;  h[5]  = ca.z >> 16;
        h[6]  = ca.w & 0xFFFFu;  h[7]  = ca.w >> 16;
        h[8]  = cb.x & 0xFFFFu;  h[9]  = cb.x >> 16;
        h[10] = cb.y & 0xFFFFu;  h[11] = cb.y >> 16;
        h[12] = cb.z & 0xFFFFu;  h[13] = cb.z >> 16;
        h[14] = cb.w & 0xFFFFu;  h[15] = cb.w >> 16;
        uint32_t Fi = above;
        for (int i = 15; i >= 0; --i) {
            Fi += h[i];
            if (Fi >= KK) { sBstar = (uint32_t)(16 * t + i); sC = Fi; break; }
        }
    }
    __syncthreads();

    const uint32_t bstar = sBstar;
    const int      C     = (int)sC;

    // ---- publish F only for buckets >= b* (thread-contiguous condition ->
    //      wave-uniform; ~75% of threads skip the unpack/pack entirely) ----
    if (16 * t + 15 >= (int)bstar) {
        uint32_t h[16];
        h[0]  = ca.x & 0xFFFFu;  h[1]  = ca.x >> 16;
        h[2]  = ca.y & 0xFFFFu;  h[3]  = ca.y >> 16;
        h[4]  = ca.z & 0xFFFFu;  h[5]  = ca.z >> 16;
        h[6]  = ca.w & 0xFFFFu;  h[7]  = ca.w >> 16;
        h[8]  = cb.x & 0xFFFFu;  h[9]  = cb.x >> 16;
        h[10] = cb.y & 0xFFFFu;  h[11] = cb.y >> 16;
        h[12] = cb.z & 0xFFFFu;  h[13] = cb.z >> 16;
        h[14] = cb.w & 0xFFFFu;  h[15] = cb.w >> 16;
        uint32_t F[17];
        F[16] = above;
        #pragma unroll
        for (int i = 15; i >= 0; --i) F[i] = F[i + 1] + h[i];
        uint4 fa, fb;
        fa.x = F[0]  | (F[1]  << 16);  fa.y = F[2]  | (F[3]  << 16);
        fa.z = F[4]  | (F[5]  << 16);  fa.w = F[6]  | (F[7]  << 16);
        fb.x = F[8]  | (F[9]  << 16);  fb.y = F[10] | (F[11] << 16);
        fb.z = F[12] | (F[13] << 16);  fb.w = F[14] | (F[15] << 16);
        ((uint4*)sF)[2 * t]     = fa;
        ((uint4*)sF)[2 * t + 1] = fb;
    }
    __syncthreads();

    // ---- compact candidates (bucket >= b*) ----
    // cursor for bucket bk is sF[bk+1] (starts at F(bk+1), ends at F(bk)).
    // 32-bit key: low20(u) << 11 | (2047-d); top-12 bits equal within a
    // bucket so truncation preserves within-bucket order; reversed index
    // makes ties rank lower d first.
    #pragma unroll
    for (int i = 0; i < 8; ++i) {
        uint32_t bk = u[i] >> 20;
        if (bk >= bstar) {
            uint32_t ci  = bk + 1;
            uint32_t sh  = (ci & 1) << 4;
            uint32_t old = atomicAdd(&sFw[ci >> 1], 1u << sh);
            uint32_t pos = (old >> sh) & 0xFFFFu;
            int d = (i < 4) ? (4 * t + i) : (1024 + 4 * t + (i - 4));
            sCand[pos]   = ((u[i] & 0xFFFFFu) << 11) | (uint32_t)(DD - 1 - d);
            sCandBk[pos] = (uint16_t)bk;
        }
    }
    __syncthreads();

    // ---- distributed rank loop (bucket-grouped => balanced wave work),
    //      ranks scatter DIRECTLY to global (no sIdx roundtrip) ----
    // post-compaction: sF[bk+1] = F(bk) (hi), sF[bk+2] = F(bk+1) (lo)
    uint16_t* orow = idxT + (size_t)b * KK * NN + n;
    for (int p = t; p < C; p += T1) {
        uint32_t key = sCand[p];
        int bk = (int)sCandBk[p];
        uint32_t hi = sF[bk + 1];
        uint32_t lo = sF[bk + 2];
        uint32_t rank = lo;
        for (uint32_t j = lo; j < hi; ++j)
            rank += (sCand[j] > key) ? 1u : 0u;
        if (rank < KK)
            orow[(size_t)rank * NN] = (uint16_t)(DD - 1 - (int)(key & 0x7FFu));
    }
}

// ---------------- Kernel 2: accumulate indicators, dense write, no atomics --
// One block = one (b,k) pair: 4096 blocks x 128 threads, 4 KB LDS histogram.
// Reads its 1000 indices as 125 contiguous uint4 (L2-resident), run-length
// aggregates before LDS atomics (rank-k index is stable across n), writes
// out[b][k][:] dense.
#define T2 128
__global__ __launch_bounds__(T2, 8) void ptopk_accum(
    const uint16_t* __restrict__ idxT,
    float* __restrict__ out)
{
    __shared__ __align__(16) uint32_t hist[DD / 2];   // 1024 words = 4 KB

    const int t   = threadIdx.x;
    const int bkx = blockIdx.x;          // = b*KK + k

    uint4 z; z.x = z.y = z.z = z.w = 0u;
    ((uint4*)hist)[t]       = z;
    ((uint4*)hist)[t + T2]  = z;
    __syncthreads();

    // 1000 uint16 = 125 uint4 per (b,k) row, contiguous
    if (t < 125) {
        uint4 v = ((const uint4*)(idxT + (size_t)bkx * NN))[t];
        uint16_t d[8];
        d[0] = (uint16_t)(v.x & 0xFFFFu); d[1] = (uint16_t)(v.x >> 16);
        d[2] = (uint16_t)(v.y & 0xFFFFu); d[3] = (uint16_t)(v.y >> 16);
        d[4] = (uint16_t)(v.z & 0xFFFFu); d[5] = (uint16_t)(v.z >> 16);
        d[6] = (uint16_t)(v.w & 0xFFFFu); d[7] = (uint16_t)(v.w >> 16);
        // run-length aggregate consecutive equal indices -> one atomic per run
        uint16_t cur = d[0];
        uint32_t run = 1;
        #pragma unroll
        for (int i = 1; i < 8; ++i) {
            if (d[i] == cur) { run++; }
            else {
                atomicAdd(&hist[cur >> 1], run << ((cur & 1) << 4));
                cur = d[i]; run = 1;
            }
        }
        atomicAdd(&hist[cur >> 1], run << ((cur & 1) << 4));
    }
    __syncthreads();

    // dense coalesced write: 2048 floats; each thread 2 uint4 -> 4 float4
    float4* out4 = (float4*)(out + (size_t)bkx * DD);
    #pragma unroll
    for (int i = 0; i < 2; ++i) {
        int j = i * T2 + t;
        uint4 wv = ((const uint4*)hist)[j];
        float4 f0, f1;
        f0.x = (float)(wv.x & 0xFFFFu) * INVN;  f0.y = (float)(wv.x >> 16) * INVN;
        f0.z = (float)(wv.y & 0xFFFFu) * INVN;  f0.w = (float)(wv.y >> 16) * INVN;
        f1.x = (float)(wv.z & 0xFFFFu) * INVN;  f1.y = (float)(wv.z >> 16) * INVN;
        f1.z = (float)(wv.w & 0xFFFFu) * INVN;  f1.w = (float)(wv.w >> 16) * INVN;
        out4[2 * j]     = f0;
        out4[2 * j + 1] = f1;
    }
}

extern "C" void kernel_launch(void* const* d_in, const int* in_sizes, int n_in,
                              void* d_out, int out_size, void* d_ws, size_t ws_size,
                              hipStream_t stream) {
    const float* x     = (const float*)d_in[0];
    const float* noise = (const float*)d_in[1];
    float* out         = (float*)d_out;
    uint16_t* idxT     = (uint16_t*)d_ws;    // BB*KK*NN*2 = 8.2 MB, transposed

    hipLaunchKernelGGL(ptopk_rank,
                       dim3(BB * NN), dim3(T1), 0, stream,
                       x, noise, idxT);
    hipLaunchKernelGGL(ptopk_accum,
                       dim3(BB * KK), dim3(T2), 0, stream,
                       idxT, out);
}

// Round 9
// 226.842 us; speedup vs baseline: 1.4664x; 1.0079x over previous
//
#include <hip/hip_runtime.h>
#include <stdint.h>

// Problem constants (fixed by reference)
#define BB    16
#define NN    1000
#define DD    2048
#define KK    256
#define SIG   0.05f
#define INVN  (1.0f / 1000.0f)

#define T1    256
#define NBUCK 4096   // 12-bit high-bits histogram
#define CMAX  1536   // candidate capacity (C = F(b*) ~ 310 for this input;
                     // overflow needs a >1280-deep crossing bucket)

// ---------------- Kernel 1: per-row exact top-K ranks -> transposed uint16 --
// One block = one (b,n) row, 256 threads x 8 elements, ~17.4 KB LDS ->
// 8 blocks/CU (32 waves = cap).
// XCD-swizzled row mapping (R7: cut idxT write amplification 8x).
// Packed uint16 histogram -> packed pair-sum suffix scan (6 barriers; the
// serial inter-wave scan is replaced by per-thread broadcast reads) ->
// crossing thread finds b* -> threads covering buckets >= b* publish F ->
// compaction into sF cursors -> distributed bucket-grouped rank loop ->
// direct global scatter of ranks.
__global__ __launch_bounds__(T1, 8) void ptopk_rank(
    const float* __restrict__ x,
    const float* __restrict__ noise,
    uint16_t* __restrict__ idxT)
{
    __shared__ __align__(16) uint16_t sF[NBUCK + 8];   // 8208 B: hist -> F(b)
    __shared__ __align__(16) uint32_t sCand[CMAX];     // 6144 B: truncated keys
    __shared__ __align__(16) uint16_t sCandBk[CMAX];   // 3072 B: bucket per slot
    __shared__ uint32_t sWS[4];                        // per-wave scan totals
    __shared__ uint32_t sBstar;                        // crossing bucket

    const int t    = threadIdx.x;
    const int lane = t & 63;
    const int w    = t >> 6;
    // XCD swizzle: consecutive n end up on one XCD -> idxT cachelines are
    // produced by a single L2 (R6->R7: WRITE_SIZE 64 MB -> 8 MB).
    const int row  = (blockIdx.x & 7) * (BB * NN / 8) + (blockIdx.x >> 3);
    const int b    = row / NN;
    const int n    = row - b * NN;

    uint32_t* sFw = (uint32_t*)sF;

    // ---- init sF: 513 uint4 = 8208 B (covers pad through sF[4103]) ----
    uint4 z; z.x = z.y = z.z = z.w = 0u;
    uint4* sF4 = (uint4*)sF;
    sF4[t]       = z;
    sF4[t + T1]  = z;
    if (t == 0) sF4[2 * T1] = z;
    __syncthreads();

    // ---- load 8 elements (two coalesced float4 per array), keys, histogram --
    const float4* nrow = (const float4*)(noise + (size_t)row * DD);
    const float4* xrow = (const float4*)(x + (size_t)b * DD);
    float4 na = nrow[t], nb = nrow[t + T1];
    float4 xa = xrow[t], xb = xrow[t + T1];

    float v[8];
    // match numpy: separate rounded mul and add (no FMA contraction)
    v[0] = __fadd_rn(xa.x, __fmul_rn(na.x, SIG));
    v[1] = __fadd_rn(xa.y, __fmul_rn(na.y, SIG));
    v[2] = __fadd_rn(xa.z, __fmul_rn(na.z, SIG));
    v[3] = __fadd_rn(xa.w, __fmul_rn(na.w, SIG));
    v[4] = __fadd_rn(xb.x, __fmul_rn(nb.x, SIG));
    v[5] = __fadd_rn(xb.y, __fmul_rn(nb.y, SIG));
    v[6] = __fadd_rn(xb.z, __fmul_rn(nb.z, SIG));
    v[7] = __fadd_rn(xb.w, __fmul_rn(nb.w, SIG));

    uint32_t u[8];
    #pragma unroll
    for (int i = 0; i < 8; ++i) {
        uint32_t ub = __float_as_uint(v[i]);
        // order-preserving map: u = ub ^ (asr31(ub) | 0x80000000)
        u[i] = ub ^ (uint32_t)(((int32_t)ub >> 31) | (int32_t)0x80000000);
        uint32_t bk = u[i] >> 20;
        atomicAdd(&sFw[bk >> 1], 1u << ((bk & 1) << 4));   // packed uint16 count
    }
    __syncthreads();

    // ---- chunk sum via packed pair-adds (counts <= 2048 so pair-sums
    //      <= 16384: no carry between halves; NO unpack needed) ----
    uint4 ca = ((const uint4*)sF)[2 * t];
    uint4 cb = ((const uint4*)sF)[2 * t + 1];
    uint32_t S = ca.x + ca.y + ca.z + ca.w + cb.x + cb.y + cb.z + cb.w;
    uint32_t csum = (S & 0xFFFFu) + (S >> 16);

    // wave-level inclusive suffix scan (higher lane = higher buckets)
    uint32_t s = csum;
    #pragma unroll
    for (int ofs = 1; ofs < 64; ofs <<= 1) {
        uint32_t o = __shfl_down(s, ofs, 64);
        s += (lane + ofs < 64) ? o : 0u;
    }
    if (lane == 0) sWS[w] = s;    // inclusive total of wave w's chunk range
    __syncthreads();

    // per-thread sum of higher waves' totals (broadcast reads, no serial step)
    uint32_t waveAbove = 0;
    #pragma unroll
    for (int i = 0; i < 4; ++i) waveAbove += (i > w) ? sWS[i] : 0u;

    const uint32_t above = waveAbove + (s - csum);     // F(16t+16)

    // ---- exactly one thread's chunk contains the crossing; it unpacks ----
    if (above < KK && above + csum >= KK) {
        uint32_t h[16];
        h[0]  = ca.x & 0xFFFFu;  h[1]  = ca.x >> 16;
        h[2]  = ca.y & 0xFFFFu;  h[3]  = ca.y >> 16;
        h[4]  = ca.z & 0xFFFFu;  h[5]  = ca.z >> 16;
        h[6]  = ca.w & 0xFFFFu;  h[7]  = ca.w >> 16;
        h[8]  = cb.x & 0xFFFFu;  h[9]  = cb.x >> 16;
        h[10] = cb.y & 0xFFFFu;  h[11] = cb.y >> 16;
        h[12] = cb.z & 0xFFFFu;  h[13] = cb.z >> 16;
        h[14] = cb.w & 0xFFFFu;  h[15] = cb.w >> 16;
        uint32_t Fi = above;
        for (int i = 15; i >= 0; --i) {
            Fi += h[i];
            if (Fi >= KK) { sBstar = (uint32_t)(16 * t + i); break; }
        }
    }
    __syncthreads();

    const uint32_t bstar = sBstar;

    // ---- publish F only for buckets >= b* (thread-contiguous condition ->
    //      wave-uniform; most threads skip the unpack/pack entirely) ----
    if (16 * t + 15 >= (int)bstar) {
        uint32_t h[16];
        h[0]  = ca.x & 0xFFFFu;  h[1]  = ca.x >> 16;
        h[2]  = ca.y & 0xFFFFu;  h[3]  = ca.y >> 16;
        h[4]  = ca.z & 0xFFFFu;  h[5]  = ca.z >> 16;
        h[6]  = ca.w & 0xFFFFu;  h[7]  = ca.w >> 16;
        h[8]  = cb.x & 0xFFFFu;  h[9]  = cb.x >> 16;
        h[10] = cb.y & 0xFFFFu;  h[11] = cb.y >> 16;
        h[12] = cb.z & 0xFFFFu;  h[13] = cb.z >> 16;
        h[14] = cb.w & 0xFFFFu;  h[15] = cb.w >> 16;
        uint32_t F[17];
        F[16] = above;
        #pragma unroll
        for (int i = 15; i >= 0; --i) F[i] = F[i + 1] + h[i];
        uint4 fa, fb;
        fa.x = F[0]  | (F[1]  << 16);  fa.y = F[2]  | (F[3]  << 16);
        fa.z = F[4]  | (F[5]  << 16);  fa.w = F[6]  | (F[7]  << 16);
        fb.x = F[8]  | (F[9]  << 16);  fb.y = F[10] | (F[11] << 16);
        fb.z = F[12] | (F[13] << 16);  fb.w = F[14] | (F[15] << 16);
        ((uint4*)sF)[2 * t]     = fa;
        ((uint4*)sF)[2 * t + 1] = fb;
    }
    __syncthreads();

    // ---- compact candidates (bucket >= b*) ----
    // cursor for bucket bk is sF[bk+1] (starts at F(bk+1), ends at F(bk));
    // sF[b*] itself is never a cursor, so it keeps F(b*) = C for later.
    // 32-bit key: low20(u) << 11 | (2047-d); top-12 bits equal within a
    // bucket so truncation preserves within-bucket order; reversed index
    // makes ties rank lower d first.
    #pragma unroll
    for (int i = 0; i < 8; ++i) {
        uint32_t bk = u[i] >> 20;
        if (bk >= bstar) {
            uint32_t ci  = bk + 1;
            uint32_t sh  = (ci & 1) << 4;
            uint32_t old = atomicAdd(&sFw[ci >> 1], 1u << sh);
            uint32_t pos = (old >> sh) & 0xFFFFu;
            int d = (i < 4) ? (4 * t + i) : (1024 + 4 * t + (i - 4));
            if (pos < CMAX) {                      // safety guard (never hit)
                sCand[pos]   = ((u[i] & 0xFFFFFu) << 11) | (uint32_t)(DD - 1 - d);
                sCandBk[pos] = (uint16_t)bk;
            }
        }
    }
    __syncthreads();

    // ---- distributed rank loop (bucket-grouped => balanced wave work),
    //      ranks scatter DIRECTLY to global ----
    // post-compaction: sF[bk+1] = F(bk) (hi), sF[bk+2] = F(bk+1) (lo)
    int C = (int)sF[bstar];                        // = F(b*)
    if (C > CMAX) C = CMAX;
    uint16_t* orow = idxT + (size_t)b * KK * NN + n;
    for (int p = t; p < C; p += T1) {
        uint32_t key = sCand[p];
        int bk = (int)sCandBk[p];
        uint32_t hi = sF[bk + 1];
        uint32_t lo = sF[bk + 2];
        uint32_t rank = lo;
        for (uint32_t j = lo; j < hi; ++j)
            rank += (sCand[j] > key) ? 1u : 0u;
        if (rank < KK)
            orow[(size_t)rank * NN] = (uint16_t)(DD - 1 - (int)(key & 0x7FFu));
    }
}

// ---------------- Kernel 2: accumulate indicators, dense write, no atomics --
// One block = one (b,k) pair: 4096 blocks x 64 threads (1 wave), 4 KB LDS.
// 16 values/thread (62x16 + 1x8): RLE collapses the long stable-index runs
// into ~1 atomic per thread, and only 63 lanes contend per address (vs 125
// at T2=128) -> same-address serialization halved; 32 blocks/CU resident.
#define T2 64
__global__ __launch_bounds__(T2) void ptopk_accum(
    const uint16_t* __restrict__ idxT,
    float* __restrict__ out)
{
    __shared__ __align__(16) uint32_t hist[DD / 2];   // 1024 words = 256 uint4

    const int t   = threadIdx.x;
    const int bkx = blockIdx.x;          // = b*KK + k

    uint4 z; z.x = z.y = z.z = z.w = 0u;
    #pragma unroll
    for (int i = 0; i < 4; ++i)
        ((uint4*)hist)[i * T2 + t] = z;
    __syncthreads();

    // thread t owns values [16t, 16t+16): uint4 slots 2t, 2t+1 of 125 total
    const uint4* src = (const uint4*)(idxT + (size_t)bkx * NN);
    const bool hasA = (t <= 62);
    const bool hasB = (t <  62);
    if (hasA) {
        uint4 va = src[2 * t];
        uint16_t dv[16];
        dv[0] = (uint16_t)(va.x & 0xFFFFu); dv[1] = (uint16_t)(va.x >> 16);
        dv[2] = (uint16_t)(va.y & 0xFFFFu); dv[3] = (uint16_t)(va.y >> 16);
        dv[4] = (uint16_t)(va.z & 0xFFFFu); dv[5] = (uint16_t)(va.z >> 16);
        dv[6] = (uint16_t)(va.w & 0xFFFFu); dv[7] = (uint16_t)(va.w >> 16);
        uint32_t cur = dv[0], run = 1;
        #pragma unroll
        for (int i = 1; i < 8; ++i) {
            if (dv[i] == cur) { run++; }
            else {
                atomicAdd(&hist[cur >> 1], run << ((cur & 1) << 4));
                cur = dv[i]; run = 1;
            }
        }
        if (hasB) {
            uint4 vb = src[2 * t + 1];
            dv[8]  = (uint16_t)(vb.x & 0xFFFFu); dv[9]  = (uint16_t)(vb.x >> 16);
            dv[10] = (uint16_t)(vb.y & 0xFFFFu); dv[11] = (uint16_t)(vb.y >> 16);
            dv[12] = (uint16_t)(vb.z & 0xFFFFu); dv[13] = (uint16_t)(vb.z >> 16);
            dv[14] = (uint16_t)(vb.w & 0xFFFFu); dv[15] = (uint16_t)(vb.w >> 16);
            #pragma unroll
            for (int i = 8; i < 16; ++i) {
                if (dv[i] == cur) { run++; }
                else {
                    atomicAdd(&hist[cur >> 1], run << ((cur & 1) << 4));
                    cur = dv[i]; run = 1;
                }
            }
        }
        atomicAdd(&hist[cur >> 1], run << ((cur & 1) << 4));
    }
    __syncthreads();

    // dense coalesced write: 2048 floats = 512 float4; each thread reads
    // 4 hist uint4 and writes 8 float4  (R8 bug: loop bound was 8 -> wrote
    // 2x the row and ran past the output buffer)
    float4* out4 = (float4*)(out + (size_t)bkx * DD);
    #pragma unroll
    for (int i = 0; i < 4; ++i) {
        int j = i * T2 + t;
        uint4 wv = ((const uint4*)hist)[j];
        float4 f0, f1;
        f0.x = (float)(wv.x & 0xFFFFu) * INVN;  f0.y = (float)(wv.x >> 16) * INVN;
        f0.z = (float)(wv.y & 0xFFFFu) * INVN;  f0.w = (float)(wv.y >> 16) * INVN;
        f1.x = (float)(wv.z & 0xFFFFu) * INVN;  f1.y = (float)(wv.z >> 16) * INVN;
        f1.z = (float)(wv.w & 0xFFFFu) * INVN;  f1.w = (float)(wv.w >> 16) * INVN;
        out4[2 * j]     = f0;
        out4[2 * j + 1] = f1;
    }
}

extern "C" void kernel_launch(void* const* d_in, const int* in_sizes, int n_in,
                              void* d_out, int out_size, void* d_ws, size_t ws_size,
                              hipStream_t stream) {
    const float* x     = (const float*)d_in[0];
    const float* noise = (const float*)d_in[1];
    float* out         = (float*)d_out;
    uint16_t* idxT     = (uint16_t*)d_ws;    // BB*KK*NN*2 = 8.2 MB, transposed

    hipLaunchKernelGGL(ptopk_rank,
                       dim3(BB * NN), dim3(T1), 0, stream,
                       x, noise, idxT);
    hipLaunchKernelGGL(ptopk_accum,
                       dim3(BB * KK), dim3(T2), 0, stream,
                       idxT, out);
}